// Round 9
// baseline (100.487 us; speedup 1.0000x reference)
//
#include <hip/hip_runtime.h>
#include <math.h>

#define EPSV 1e-5f

typedef float f4v __attribute__((ext_vector_type(4)));

__device__ __forceinline__ float waveReduceSum(float v) {
#pragma unroll
    for (int o = 32; o > 0; o >>= 1) v += __shfl_down(v, o, 64);
    return v;
}

// ---------------------------------------------------------------------------
// K1: K[n,c] = elu(cls@wq.T + bq)+1 ; Q[n,c] = (elu(cls@wk.T + bk)+1)/16
//     Kw[n,c] = K * ln_w[c]
// one wave per (n,c); 2048 blocks x 256 threads (4 waves each).  [R1-proven]
__global__ void k_kq(const float* __restrict__ cls,
                     const float* __restrict__ wq, const float* __restrict__ bq,
                     const float* __restrict__ wk, const float* __restrict__ bk,
                     const float* __restrict__ ln_w,
                     float* __restrict__ Kb, float* __restrict__ Qb,
                     float* __restrict__ Kw) {
    int w = blockIdx.x * 4 + (threadIdx.x >> 6); // 0..8191
    int lane = threadIdx.x & 63;
    int n = w >> 8, c = w & 255;
    const float* cp = cls + (size_t)n * 512;
    const float* qp = wq + (size_t)c * 512;
    const float* kp = wk + (size_t)c * 512;
    float aK = 0.f, aQ = 0.f;
#pragma unroll
    for (int i = 0; i < 8; ++i) {
        int kk = lane + i * 64;
        float cv = cp[kk];
        aK += cv * qp[kk];
        aQ += cv * kp[kk];
    }
    aK = waveReduceSum(aK);
    aQ = waveReduceSum(aQ);
    if (lane == 0) {
        float xk = aK + bq[c];
        float xq = aQ + bk[c];
        float Kv = (xk > 0.f ? xk : expf(xk) - 1.f) + 1.f;
        float Qv = ((xq > 0.f ? xq : expf(xq) - 1.f) + 1.f) * 0.0625f;
        Kb[w] = Kv;
        Qb[w] = Qv;
        Kw[w] = Kv * ln_w[c];
    }
}

// ---------------------------------------------------------------------------
// K2 (k_stats): pure X read (the only HBM read of X).
//   Sp/S2p[block,g] = per-tile partial sum/sumsq of X over group channels.
// grid 512 = n*16+tile; 512 threads (8 waves); wave wv owns groups 8wv..8wv+7.
// [= R1-proven pass1 with the W store deleted]
__global__ void __launch_bounds__(512) k_stats(
        const float* __restrict__ X,
        float* __restrict__ Sp, float* __restrict__ S2p) {
    int n = blockIdx.x >> 4, tile = blockIdx.x & 15;
    int wv = threadIdx.x >> 6, lane = threadIdx.x & 63;
    int pix = tile * 256 + lane * 4;
    const float* xb = X + ((size_t)n * 256 << 12) + pix;
#pragma unroll
    for (int go = 0; go < 8; ++go) {
        int g = wv * 8 + go;
        int c0 = g * 4;
        float s = 0.f, s2 = 0.f;
#pragma unroll
        for (int j = 0; j < 4; ++j) {
            float4 v = *(const float4*)(xb + ((size_t)(c0 + j) << 12));
            s  += v.x + v.y + v.z + v.w;
            s2 += v.x * v.x + v.y * v.y + v.z * v.z + v.w * v.w;
        }
        s = waveReduceSum(s);
        s2 = waveReduceSum(s2);
        if (lane == 0) {
            Sp[blockIdx.x * 64 + g] = s;
            S2p[blockIdx.x * 64 + g] = s2;
        }
    }
}

// ---------------------------------------------------------------------------
// K3 (k_sf): s directly from X (L3-hot re-read; R4 FETCH evidence).
// Prologue: wave0 reduces Sp/S2p -> iv per group + B[n]; A[c]=Kw[c]*iv_g.
// Main: wave wv accumulates channels 32wv..32wv+31 for its 256-pixel tile
// (float4/lane), partials combined through LDS. Block s-moment partials.
// tile==0 blocks also compute R[n,:] = conv_w @ Q.
// grid 512 = n*16+tile; 512 threads.
__global__ void __launch_bounds__(512) k_sf(
        const float* __restrict__ X,
        const float* __restrict__ Sp, const float* __restrict__ S2p,
        const float* __restrict__ Kb, const float* __restrict__ Kw,
        const float* __restrict__ ln_b,
        const float* __restrict__ Qb, const float* __restrict__ conv_w,
        float* __restrict__ sbuf,
        float* __restrict__ p1, float* __restrict__ p2,
        float* __restrict__ R) {
    int n = blockIdx.x >> 4, tile = blockIdx.x & 15;
    int t = threadIdx.x, wv = t >> 6, lane = t & 63;
    __shared__ float ivs[64];
    __shared__ float aS[256];
    __shared__ float partS[8][256];
    __shared__ float qs[256];
    __shared__ float q1[4], q2[4];
    __shared__ float Bsh;

    if (t < 64) {
        float S = 0.f, S2 = 0.f;
#pragma unroll
        for (int tl = 0; tl < 16; ++tl) {
            S  += Sp[(n * 16 + tl) * 64 + t];
            S2 += S2p[(n * 16 + tl) * 64 + t];
        }
        float mu = S * (1.f / 16384.f);
        float var = S2 * (1.f / 16384.f) - mu * mu;
        float iv = rsqrtf(var + EPSV);
        ivs[t] = iv;
        float t1 = 0.f, t2 = 0.f;
#pragma unroll
        for (int j = 0; j < 4; ++j) {
            int c = t * 4 + j;
            t1 += Kb[n * 256 + c] * ln_b[c];
            t2 += Kw[n * 256 + c];
        }
        float r = waveReduceSum(t1 - iv * mu * t2);
        if (t == 0) Bsh = r;
    }
    __syncthreads();
    if (t < 256) aS[t] = Kw[n * 256 + t] * ivs[t >> 2];
    __syncthreads();

    int pix = tile * 256 + lane * 4;
    const float* xb = X + ((size_t)n * 256 << 12) + pix;
    float ax = 0.f, ay = 0.f, az = 0.f, aw = 0.f;
#pragma unroll 8
    for (int j = 0; j < 32; ++j) {
        int c = wv * 32 + j;
        float4 v = *(const float4*)(xb + ((size_t)c << 12));
        float a = aS[c];
        ax += a * v.x; ay += a * v.y; az += a * v.z; aw += a * v.w;
    }
    float4 part = {ax, ay, az, aw};
    *(float4*)(&partS[wv][lane * 4]) = part;
    __syncthreads();

    if (t < 256) {
        float s = Bsh;
#pragma unroll
        for (int w = 0; w < 8; ++w) s += partS[w][t];
        sbuf[n * 4096 + tile * 256 + t] = s;
        float r1 = waveReduceSum(s);
        float r2 = waveReduceSum(s * s);
        if (lane == 0) { q1[wv] = r1; q2[wv] = r2; }
    }
    __syncthreads();
    if (t == 0) {
        p1[blockIdx.x] = q1[0] + q1[1] + q1[2] + q1[3];
        p2[blockIdx.x] = q2[0] + q2[1] + q2[2] + q2[3];
    }

    if (tile == 0) {
        if (t < 256) qs[t] = Qb[n * 256 + t];
        __syncthreads();
        if (t < 256) {
            const float4* cw = (const float4*)(conv_w + (size_t)t * 256);
            const float4* q4 = (const float4*)qs;
            float acc = 0.f;
#pragma unroll 8
            for (int k = 0; k < 64; ++k) {
                float4 w4 = cw[k], v4 = q4[k];
                acc += w4.x * v4.x + w4.y * v4.y + w4.z * v4.z + w4.w * v4.w;
            }
            R[n * 256 + t] = acc;
        }
    }
}

// ---------------------------------------------------------------------------
// K4 (k_final): flat layout + inline alpha/beta (o uniform per block) + NT
// store.  grid 32768 x 256.  [R7 form; p-partials now 16 per n]
__global__ void __launch_bounds__(256) k_final(
        const float* __restrict__ X, const float* __restrict__ sbuf,
        const float* __restrict__ p1, const float* __restrict__ p2,
        const float* __restrict__ R, const float* __restrict__ conv_b,
        const float* __restrict__ gn_w, const float* __restrict__ gn_b,
        float* __restrict__ out) {
    size_t idx4 = (size_t)blockIdx.x * 256 + threadIdx.x;
    size_t e0 = (size_t)blockIdx.x * 1024;   // block-uniform
    int n = (int)(e0 >> 20);
    int o = (int)((e0 & 1048575) >> 12);     // uniform within block

    float a1 = 0.f, a2 = 0.f;
#pragma unroll
    for (int i = 0; i < 16; ++i) { a1 += p1[n * 16 + i]; a2 += p2[n * 16 + i]; }
    float Ms1 = a1 * (1.f / 4096.f);
    float Ms2 = a2 * (1.f / 4096.f);
    int g4 = o & ~3;
    float mR = 0.f, mR2 = 0.f, mRb = 0.f, mb = 0.f, mb2 = 0.f;
#pragma unroll
    for (int j = 0; j < 4; ++j) {
        float r = R[n * 256 + g4 + j];
        float bb = conv_b[g4 + j];
        mR += r; mR2 += r * r; mRb += r * bb; mb += bb; mb2 += bb * bb;
    }
    mR *= 0.25f; mR2 *= 0.25f; mRb *= 0.25f; mb *= 0.25f; mb2 *= 0.25f;
    float mu = Ms1 * mR + mb;
    float var = Ms2 * mR2 + 2.f * Ms1 * mRb + mb2 - mu * mu;
    float iv = rsqrtf(var + EPSV);
    float gw = gn_w[o];
    float a = R[n * 256 + o] * iv * gw;
    float b = (conv_b[o] - mu) * iv * gw + gn_b[o];

    size_t e = idx4 * 4;
    int pix = (int)(e & 4095);
    float4 x = ((const float4*)X)[idx4];
    float4 s = *(const float4*)(sbuf + n * 4096 + pix);
    f4v r;
    r.x = fmaf(s.x, a, b) + x.x;
    r.y = fmaf(s.y, a, b) + x.y;
    r.z = fmaf(s.z, a, b) + x.z;
    r.w = fmaf(s.w, a, b) + x.w;
    __builtin_nontemporal_store(r, (f4v*)out + idx4);
}

// ---------------------------------------------------------------------------
extern "C" void kernel_launch(void* const* d_in, const int* in_sizes, int n_in,
                              void* d_out, int out_size, void* d_ws, size_t ws_size,
                              hipStream_t stream) {
    const float* X      = (const float*)d_in[0];
    const float* cls    = (const float*)d_in[1];
    const float* ln_w   = (const float*)d_in[2];
    const float* ln_b   = (const float*)d_in[3];
    const float* wq     = (const float*)d_in[4];
    const float* bq     = (const float*)d_in[5];
    const float* wk     = (const float*)d_in[6];
    const float* bk     = (const float*)d_in[7];
    const float* conv_w = (const float*)d_in[8];
    const float* conv_b = (const float*)d_in[9];
    const float* gn_w   = (const float*)d_in[10];
    const float* gn_b   = (const float*)d_in[11];

    float* ws = (float*)d_ws;
    float* Kb    = ws;            // 8192
    float* Qb    = ws + 8192;     // 8192
    float* Kw    = ws + 16384;    // 8192
    float* Sp    = ws + 24576;    // 32768
    float* S2p   = ws + 57344;    // 32768
    float* p1    = ws + 90112;    // 512
    float* p2    = ws + 90624;    // 512
    float* R     = ws + 91136;    // 8192
    float* sbuf  = ws + 131072;   // 131072 (16B aligned)

    k_kq<<<2048, 256, 0, stream>>>(cls, wq, bq, wk, bk, ln_w, Kb, Qb, Kw);
    k_stats<<<512, 512, 0, stream>>>(X, Sp, S2p);
    k_sf<<<512, 512, 0, stream>>>(X, Sp, S2p, Kb, Kw, ln_b, Qb, conv_w,
                                  sbuf, p1, p2, R);
    k_final<<<32768, 256, 0, stream>>>(X, sbuf, p1, p2, R, conv_b, gn_w, gn_b,
                                       (float*)d_out);
}

// Round 10
// 87.911 us; speedup vs baseline: 1.1430x; 1.1430x over previous
//
#include <hip/hip_runtime.h>
#include <math.h>

#define EPSV 1e-5f

typedef float f4v __attribute__((ext_vector_type(4)));
typedef _Float16 h4v __attribute__((ext_vector_type(4)));
typedef _Float16 h2v __attribute__((ext_vector_type(2)));

__device__ __forceinline__ float waveReduceSum(float v) {
#pragma unroll
    for (int o = 32; o > 0; o >>= 1) v += __shfl_down(v, o, 64);
    return v;
}

// ---------------------------------------------------------------------------
// K1: K[n,c] = elu(cls@wq.T + bq)+1 ; Q[n,c] = (elu(cls@wk.T + bk)+1)/16
//     Kw[n,c] = K * ln_w[c]
// one wave per (n,c); 2048 blocks x 256 threads.  [R1-proven, untouched]
__global__ void k_kq(const float* __restrict__ cls,
                     const float* __restrict__ wq, const float* __restrict__ bq,
                     const float* __restrict__ wk, const float* __restrict__ bk,
                     const float* __restrict__ ln_w,
                     float* __restrict__ Kb, float* __restrict__ Qb,
                     float* __restrict__ Kw) {
    int w = blockIdx.x * 4 + (threadIdx.x >> 6); // 0..8191
    int lane = threadIdx.x & 63;
    int n = w >> 8, c = w & 255;
    const float* cp = cls + (size_t)n * 512;
    const float* qp = wq + (size_t)c * 512;
    const float* kp = wk + (size_t)c * 512;
    float aK = 0.f, aQ = 0.f;
#pragma unroll
    for (int i = 0; i < 8; ++i) {
        int kk = lane + i * 64;
        float cv = cp[kk];
        aK += cv * qp[kk];
        aQ += cv * kp[kk];
    }
    aK = waveReduceSum(aK);
    aQ = waveReduceSum(aQ);
    if (lane == 0) {
        float xk = aK + bq[c];
        float xq = aQ + bk[c];
        float Kv = (xk > 0.f ? xk : expf(xk) - 1.f) + 1.f;
        float Qv = ((xq > 0.f ? xq : expf(xq) - 1.f) + 1.f) * 0.0625f;
        Kb[w] = Kv;
        Qb[w] = Qv;
        Kw[w] = Kv * ln_w[c];
    }
}

// ---------------------------------------------------------------------------
// K2 (pass1): single HBM read of X producing
//   W[n,g,p] (fp16, 16.75 MB) = sum_{c in g} Kw[n,c]*X[n,c,p]
//   Sp/S2p[block,g] = per-tile partial sum/sumsq of X over group channels
// grid 512 = n*16+tile; 512 threads (8 waves).  [R1 structure; fp16 W store]
__global__ void __launch_bounds__(512) k_pass1(
        const float* __restrict__ X, const float* __restrict__ Kw,
        _Float16* __restrict__ W, float* __restrict__ Sp, float* __restrict__ S2p) {
    int n = blockIdx.x >> 4, tile = blockIdx.x & 15;
    int wv = threadIdx.x >> 6, lane = threadIdx.x & 63;
    __shared__ float kws[256];
    if (threadIdx.x < 256) kws[threadIdx.x] = Kw[n * 256 + threadIdx.x];
    __syncthreads();
    int pix = tile * 256 + lane * 4;
    const float* xb = X + ((size_t)n * 256 << 12) + pix;
#pragma unroll
    for (int go = 0; go < 8; ++go) {
        int g = wv * 8 + go;
        int c0 = g * 4;
        float ax = 0.f, ay = 0.f, az = 0.f, aw = 0.f;
        float s = 0.f, s2 = 0.f;
#pragma unroll
        for (int j = 0; j < 4; ++j) {
            float4 v = *(const float4*)(xb + ((size_t)(c0 + j) << 12));
            float kv = kws[c0 + j];
            ax += kv * v.x; ay += kv * v.y; az += kv * v.z; aw += kv * v.w;
            s  += v.x + v.y + v.z + v.w;
            s2 += v.x * v.x + v.y * v.y + v.z * v.z + v.w * v.w;
        }
        h4v hv = {(_Float16)ax, (_Float16)ay, (_Float16)az, (_Float16)aw};
        *(h4v*)(W + ((size_t)(n * 64 + g) << 12) + pix) = hv;
        s = waveReduceSum(s);
        s2 = waveReduceSum(s2);
        if (lane == 0) {
            Sp[blockIdx.x * 64 + g] = s;
            S2p[blockIdx.x * 64 + g] = s2;
        }
    }
}

// ---------------------------------------------------------------------------
// K3 (k_s): wave0 reduces Sp/S2p -> iv per group + B[n] inline; all threads:
// s = sum_g iv_g*W_g + B; block s-moment partials. Block (n,t') covers
// pass1-tiles {t', t'+8} -> same-XCD L2 hits under bid%8 round-robin.
// tile==0 blocks also compute R[n,:] = conv_w @ Q.
// grid 256 = n*8+tile; 256 threads; thread handles one half2 (2 pixels).
__global__ void k_s(const _Float16* __restrict__ W,
                    const float* __restrict__ Sp, const float* __restrict__ S2p,
                    const float* __restrict__ Kb, const float* __restrict__ Kw,
                    const float* __restrict__ ln_b,
                    const float* __restrict__ Qb, const float* __restrict__ conv_w,
                    float* __restrict__ sbuf,
                    float* __restrict__ p1, float* __restrict__ p2,
                    float* __restrict__ R) {
    int n = blockIdx.x >> 3, tile = blockIdx.x & 7;
    int t = threadIdx.x;
    __shared__ float ivs[64];
    __shared__ float Bsh;
    __shared__ float q1[4], q2[4];
    __shared__ float qs[256];
    if (t < 64) {
        float S = 0.f, S2 = 0.f;
#pragma unroll
        for (int tl = 0; tl < 16; ++tl) {
            S  += Sp[(n * 16 + tl) * 64 + t];
            S2 += S2p[(n * 16 + tl) * 64 + t];
        }
        float mu = S * (1.f / 16384.f);
        float var = S2 * (1.f / 16384.f) - mu * mu;
        float iv = rsqrtf(var + EPSV);
        ivs[t] = iv;
        float t1 = 0.f, t2 = 0.f;
#pragma unroll
        for (int j = 0; j < 4; ++j) {
            int c = t * 4 + j;
            t1 += Kb[n * 256 + c] * ln_b[c];
            t2 += Kw[n * 256 + c];
        }
        float r = waveReduceSum(t1 - iv * mu * t2);
        if (t == 0) Bsh = r;
    }
    __syncthreads();
    // pixel mapping: chunk 0 = tile, chunk 1 = tile+8 (same writer XCD)
    int chunk = t >> 7;
    int pix = (tile + chunk * 8) * 256 + (t & 127) * 2;
    const _Float16* wb = W + ((size_t)n * 64 << 12) + pix;
    float Bn = Bsh;
    float sx = Bn, sy = Bn;
#pragma unroll 16
    for (int g = 0; g < 64; ++g) {
        h2v v = *(const h2v*)(wb + ((size_t)g << 12));
        float iv = ivs[g];
        sx += iv * (float)v.x; sy += iv * (float)v.y;
    }
    float2 s2v = {sx, sy};
    *(float2*)(sbuf + n * 4096 + pix) = s2v;
    float r1 = waveReduceSum(sx + sy);
    float r2 = waveReduceSum(sx * sx + sy * sy);
    int lane = t & 63, wid = t >> 6;
    if (lane == 0) { q1[wid] = r1; q2[wid] = r2; }
    __syncthreads();
    if (t == 0) {
        p1[blockIdx.x] = q1[0] + q1[1] + q1[2] + q1[3];
        p2[blockIdx.x] = q2[0] + q2[1] + q2[2] + q2[3];
    }
    if (tile == 0) {
        qs[t] = Qb[n * 256 + t];
        __syncthreads();
        const float4* cw = (const float4*)(conv_w + (size_t)t * 256);
        const float4* q4 = (const float4*)qs;
        float acc = 0.f;
#pragma unroll 8
        for (int k = 0; k < 64; ++k) {
            float4 w4 = cw[k], v4 = q4[k];
            acc += w4.x * v4.x + w4.y * v4.y + w4.z * v4.z + w4.w * v4.w;
        }
        R[n * 256 + t] = acc;
    }
}

// ---------------------------------------------------------------------------
// K4 (k_final): flat layout + inline alpha/beta (o uniform per block) + NT
// store.  grid 32768 x 256.  [R7-proven, untouched]
__global__ void __launch_bounds__(256) k_final(
        const float* __restrict__ X, const float* __restrict__ sbuf,
        const float* __restrict__ p1, const float* __restrict__ p2,
        const float* __restrict__ R, const float* __restrict__ conv_b,
        const float* __restrict__ gn_w, const float* __restrict__ gn_b,
        float* __restrict__ out) {
    size_t idx4 = (size_t)blockIdx.x * 256 + threadIdx.x;
    size_t e0 = (size_t)blockIdx.x * 1024;   // block-uniform
    int n = (int)(e0 >> 20);
    int o = (int)((e0 & 1048575) >> 12);     // uniform within block

    float a1 = 0.f, a2 = 0.f;
#pragma unroll
    for (int i = 0; i < 8; ++i) { a1 += p1[n * 8 + i]; a2 += p2[n * 8 + i]; }
    float Ms1 = a1 * (1.f / 4096.f);
    float Ms2 = a2 * (1.f / 4096.f);
    int g4 = o & ~3;
    float mR = 0.f, mR2 = 0.f, mRb = 0.f, mb = 0.f, mb2 = 0.f;
#pragma unroll
    for (int j = 0; j < 4; ++j) {
        float r = R[n * 256 + g4 + j];
        float bb = conv_b[g4 + j];
        mR += r; mR2 += r * r; mRb += r * bb; mb += bb; mb2 += bb * bb;
    }
    mR *= 0.25f; mR2 *= 0.25f; mRb *= 0.25f; mb *= 0.25f; mb2 *= 0.25f;
    float mu = Ms1 * mR + mb;
    float var = Ms2 * mR2 + 2.f * Ms1 * mRb + mb2 - mu * mu;
    float iv = rsqrtf(var + EPSV);
    float gw = gn_w[o];
    float a = R[n * 256 + o] * iv * gw;
    float b = (conv_b[o] - mu) * iv * gw + gn_b[o];

    size_t e = idx4 * 4;
    int pix = (int)(e & 4095);
    float4 x = ((const float4*)X)[idx4];
    float4 s = *(const float4*)(sbuf + n * 4096 + pix);
    f4v r;
    r.x = fmaf(s.x, a, b) + x.x;
    r.y = fmaf(s.y, a, b) + x.y;
    r.z = fmaf(s.z, a, b) + x.z;
    r.w = fmaf(s.w, a, b) + x.w;
    __builtin_nontemporal_store(r, (f4v*)out + idx4);
}

// ---------------------------------------------------------------------------
extern "C" void kernel_launch(void* const* d_in, const int* in_sizes, int n_in,
                              void* d_out, int out_size, void* d_ws, size_t ws_size,
                              hipStream_t stream) {
    const float* X      = (const float*)d_in[0];
    const float* cls    = (const float*)d_in[1];
    const float* ln_w   = (const float*)d_in[2];
    const float* ln_b   = (const float*)d_in[3];
    const float* wq     = (const float*)d_in[4];
    const float* bq     = (const float*)d_in[5];
    const float* wk     = (const float*)d_in[6];
    const float* bk     = (const float*)d_in[7];
    const float* conv_w = (const float*)d_in[8];
    const float* conv_b = (const float*)d_in[9];
    const float* gn_w   = (const float*)d_in[10];
    const float* gn_b   = (const float*)d_in[11];

    float* ws = (float*)d_ws;
    float* Kb    = ws;            // 8192
    float* Qb    = ws + 8192;     // 8192
    float* Kw    = ws + 16384;    // 8192
    float* Sp    = ws + 24576;    // 32768
    float* S2p   = ws + 57344;    // 32768
    float* p1    = ws + 90112;    // 256
    float* p2    = ws + 90368;    // 256
    float* R     = ws + 90624;    // 8192
    float* sbuf  = ws + 131072;   // 131072 (16B aligned)
    _Float16* W  = (_Float16*)(ws + 262144); // 8,388,608 halfs = 16.75 MB

    k_kq<<<2048, 256, 0, stream>>>(cls, wq, bq, wk, bk, ln_w, Kb, Qb, Kw);
    k_pass1<<<512, 512, 0, stream>>>(X, Kw, W, Sp, S2p);
    k_s<<<256, 256, 0, stream>>>(W, Sp, S2p, Kb, Kw, ln_b, Qb, conv_w,
                                 sbuf, p1, p2, R);
    k_final<<<32768, 256, 0, stream>>>(X, sbuf, p1, p2, R, conv_b, gn_w, gn_b,
                                       (float*)d_out);
}